// Round 1
// baseline (58.165 us; speedup 1.0000x reference)
//
#include <hip/hip_runtime.h>
#include <math.h>

#define B_ 8
#define S_ 2048
#define D_ 128
#define K_ 64
#define CH 4            // chunks over S in k1
#define SIG_ 0.5f
#define EPS_ 10.0f
#define E_ 2.718281828459045f

// ---------------- K1: per (chunk, b, k) class stats ----------------
// grid = CH*B*K_ blocks (bx = (b*K+k)*CH + c), 128 threads (one per d)
__global__ void k1_class_stats(const float* __restrict__ F, const int* __restrict__ L,
                               float* __restrict__ pfsum, float* __restrict__ pssum,
                               float* __restrict__ pcnt) {
    int bx = blockIdx.x;
    int c = bx & (CH - 1);
    int k = (bx >> 2) & (K_ - 1);
    int b = bx >> 8;
    int t = threadIdx.x;  // 0..127

    __shared__ int lab[S_ / CH];
    const int s0 = c * (S_ / CH);
    for (int i = t; i < S_ / CH; i += 128) lab[i] = L[b * S_ + s0 + i];
    __syncthreads();

    float facc = 0.f, f2 = 0.f;
    int cnt = 0;
    const float* Fb = F + ((size_t)(b * S_ + s0)) * D_ + t;
    for (int s = 0; s < S_ / CH; ++s) {
        if (lab[s] == k) {            // block-uniform branch
            float v = Fb[(size_t)s * D_];
            facc += v;
            f2 = fmaf(v, v, f2);
            cnt++;
        }
    }

    int idx = (c * B_ + b) * K_ + k;
    pfsum[(size_t)idx * D_ + t] = facc;

    __shared__ float red[128];
    red[t] = f2;
    __syncthreads();
    for (int off = 64; off > 0; off >>= 1) {
        if (t < off) red[t] += red[t + off];
        __syncthreads();
    }
    if (t == 0) { pssum[idx] = red[0]; pcnt[idx] = (float)cnt; }
}

// ---------------- K2: combine chunks -> fsumK/ssumK/cntK ----------------
// grid = B*K blocks, 128 threads
__global__ void k2_finalize(const float* __restrict__ pfsum, const float* __restrict__ pssum,
                            const float* __restrict__ pcnt, float* __restrict__ fsumK,
                            float* __restrict__ ssumK, float* __restrict__ cntK) {
    int bx = blockIdx.x;
    int t = threadIdx.x;
    float s = 0.f;
    #pragma unroll
    for (int c = 0; c < CH; ++c) s += pfsum[(size_t)(c * B_ * K_ + bx) * D_ + t];
    fsumK[(size_t)bx * D_ + t] = s;
    if (t == 0) {
        float a = 0.f, n = 0.f;
        #pragma unroll
        for (int c = 0; c < CH; ++c) { a += pssum[c * B_ * K_ + bx]; n += pcnt[c * B_ * K_ + bx]; }
        ssumK[bx] = a;
        cntK[bx] = n;
    }
}

// ---------------- K2b: per-batch totals ----------------
// grid = B blocks, 128 threads
__global__ void k2b_totals(const float* __restrict__ fsumK, const float* __restrict__ ssumK,
                           float* __restrict__ fsumA, float* __restrict__ ssumA) {
    int b = blockIdx.x;
    int t = threadIdx.x;
    float s = 0.f;
    for (int k = 0; k < K_; ++k) s += fsumK[(size_t)(b * K_ + k) * D_ + t];
    fsumA[b * D_ + t] = s;
    if (t == 0) {
        float a = 0.f;
        for (int k = 0; k < K_; ++k) a += ssumK[b * K_ + k];
        ssumA[b] = a;
    }
}

// ---------------- K3: main per-anchor kernel ----------------
// grid = 512 blocks x 256 threads; each wave handles one octet (8 anchors)
__global__ void __launch_bounds__(256) k3_main(
    const float* __restrict__ F, const float* __restrict__ C,
    const float* __restrict__ phi, const int* __restrict__ L,
    const float* __restrict__ fsumK, const float* __restrict__ ssumK,
    const float* __restrict__ cntK, const float* __restrict__ fsumA,
    const float* __restrict__ ssumA, float* __restrict__ partial) {

    __shared__ float Cs[K_ * 129];   // padded rows: bank = (k+d)%32, conflict-free
    __shared__ float wacc[4];
    int tid = threadIdx.x;

    // stage centroids (coalesced read, conflict-free write)
    for (int i = tid; i < K_ * D_; i += 256) {
        int k = i >> 7, d = i & 127;
        Cs[k * 129 + d] = C[i];
    }
    __syncthreads();

    int lane = tid & 63;
    int wid = __builtin_amdgcn_readfirstlane(tid) >> 6;  // SGPR wave id

    // per-lane centroid constants (lane == k)
    float csq = 0.f;
    #pragma unroll 8
    for (int d = 0; d < D_; ++d) {
        float v = Cs[lane * 129 + d];
        csq = fmaf(v, v, csq);
    }
    float phv = phi[lane];

    int o = blockIdx.x * 4 + wid;   // octet index [0, 2048)
    int b = o >> 8;                 // 256 octets per batch
    int a0 = o * 8;                 // global anchor base (flat over B*S)

    const float4* F4 = (const float4*)F;

    // ---- phase A: per-anchor stats, 8 lanes per anchor ----
    int j_of = lane >> 3, q = lane & 7;
    int a_mine = a0 + j_of;
    int lbl_p = L[a_mine];
    float cnt_p = cntK[b * K_ + lbl_p];
    float ssm_p = ssumK[b * K_ + lbl_p];

    const float4* fr = F4 + (size_t)a_mine * 32;
    const float4* fk = (const float4*)(fsumK + (size_t)(b * K_ + lbl_p) * D_);
    const float4* fa = (const float4*)(fsumA + (size_t)b * D_);

    float sq_p = 0.f, dk_p = 0.f, da_p = 0.f;
    #pragma unroll
    for (int i = 0; i < 4; ++i) {
        int dq = i * 8 + q;                      // coalesced within 8-lane group
        float4 fv = fr[dq];
        float4 kv = fk[dq];
        float4 av = fa[dq];
        sq_p = fmaf(fv.x, fv.x, fmaf(fv.y, fv.y, fmaf(fv.z, fv.z, fmaf(fv.w, fv.w, sq_p))));
        dk_p = fmaf(fv.x, kv.x, fmaf(fv.y, kv.y, fmaf(fv.z, kv.z, fmaf(fv.w, kv.w, dk_p))));
        da_p = fmaf(fv.x, av.x, fmaf(fv.y, av.y, fmaf(fv.z, av.z, fmaf(fv.w, av.w, da_p))));
    }
    #pragma unroll
    for (int m = 1; m < 8; m <<= 1) {
        sq_p += __shfl_xor(sq_p, m);
        dk_p += __shfl_xor(dk_p, m);
        da_p += __shfl_xor(da_p, m);
    }

    // ---- phase B: centroid dots, lane = k, uniform f loads ----
    float facc[8];
    #pragma unroll
    for (int j = 0; j < 8; ++j) facc[j] = 0.f;

    for (int dq = 0; dq < 32; ++dq) {
        float4 fv[8];
        #pragma unroll
        for (int j = 0; j < 8; ++j) fv[j] = F4[(size_t)(a0 + j) * 32 + dq];  // wave-uniform addr
        #pragma unroll
        for (int l = 0; l < 4; ++l) {
            float cs = Cs[lane * 129 + (dq << 2) + l];
            #pragma unroll
            for (int j = 0; j < 8; ++j) {
                float fe = (l == 0) ? fv[j].x : (l == 1) ? fv[j].y : (l == 2) ? fv[j].z : fv[j].w;
                facc[j] = fmaf(fe, cs, facc[j]);
            }
        }
    }

    // ---- phase C: per-anchor scalar epilogue ----
    float ssA = ssumA[b];
    float acc = 0.f;
    #pragma unroll
    for (int j = 0; j < 8; ++j) {
        float sq_j = __shfl(sq_p, j * 8);
        float dk_j = __shfl(dk_p, j * 8);
        float da_j = __shfl(da_p, j * 8);
        int lbl_j = __shfl(lbl_p, j * 8);
        float cnt_j = __shfl(cnt_p, j * 8);
        float ssm_j = __shfl(ssm_p, j * 8);

        float cd2 = (sq_j + csq - 2.f * facc[j]) * (1.f / D_);
        cd2 = fmaxf(cd2, 0.f) / phv;

        float s_cd = cd2;
        #pragma unroll
        for (int m = 1; m < 64; m <<= 1) s_cd += __shfl_xor(s_cd, m);
        float pos_cent = __shfl(cd2, lbl_j);

        float ncx = (s_cd - pos_cent) * (1.f / (K_ - 1));
        float S_same = (cnt_j * sq_j + ssm_j - 2.f * dk_j) * (1.f / D_);
        float S_all = ((float)S_ * sq_j + ssA - 2.f * da_j) * (1.f / D_);
        float pos_x = fmaxf(S_same, 0.f) / fmaxf(cnt_j - 1.f, 1.f);
        float neg_cnt = (float)S_ - cnt_j;
        float neg_x = fmaxf(S_all - S_same, 0.f) / fmaxf(neg_cnt, 1.f);

        float neg_sup = neg_x * logf(neg_x + E_);
        float ncl = ncx * logf(ncx + E_);

        float pa = SIG_ * pos_x + (1.f - SIG_) * pos_cent
                 - (SIG_ * neg_sup + (1.f - SIG_) * ncl) + EPS_;
        if (neg_cnt > 0.5f) acc += pa;
    }

    if (lane == 0) wacc[wid] = acc;
    __syncthreads();
    if (tid == 0) partial[blockIdx.x] = wacc[0] + wacc[1] + wacc[2] + wacc[3];
}

// ---------------- K4: final reduce ----------------
__global__ void k4_reduce(const float* __restrict__ partial, float* __restrict__ out) {
    int t = threadIdx.x;  // 256
    float v = partial[t] + partial[t + 256];
    #pragma unroll
    for (int m = 1; m < 64; m <<= 1) v += __shfl_xor(v, m);
    __shared__ float w[4];
    if ((t & 63) == 0) w[t >> 6] = v;
    __syncthreads();
    if (t == 0) out[0] = (w[0] + w[1] + w[2] + w[3]) * (1.0f / (float)S_);
}

extern "C" void kernel_launch(void* const* d_in, const int* in_sizes, int n_in,
                              void* d_out, int out_size, void* d_ws, size_t ws_size,
                              hipStream_t stream) {
    const float* F = (const float*)d_in[0];    // [B,S,D]
    const float* C = (const float*)d_in[1];    // [K,D]
    const float* phi = (const float*)d_in[2];  // [K]
    const int* L = (const int*)d_in[3];        // [B,S]
    float* out = (float*)d_out;

    float* ws = (float*)d_ws;
    float* pfsum = ws;                               // CH*B*K*D = 262144
    float* pssum = pfsum + (size_t)CH * B_ * K_ * D_; // 2048
    float* pcnt  = pssum + CH * B_ * K_;              // 2048
    float* fsumK = pcnt + CH * B_ * K_;               // B*K*D = 65536
    float* ssumK = fsumK + (size_t)B_ * K_ * D_;      // 512
    float* cntK  = ssumK + B_ * K_;                   // 512
    float* fsumA = cntK + B_ * K_;                    // B*D = 1024
    float* ssumA = fsumA + B_ * D_;                   // 8
    float* partial = ssumA + B_;                      // 512

    k1_class_stats<<<CH * B_ * K_, 128, 0, stream>>>(F, L, pfsum, pssum, pcnt);
    k2_finalize<<<B_ * K_, 128, 0, stream>>>(pfsum, pssum, pcnt, fsumK, ssumK, cntK);
    k2b_totals<<<B_, 128, 0, stream>>>(fsumK, ssumK, fsumA, ssumA);
    k3_main<<<512, 256, 0, stream>>>(F, C, phi, L, fsumK, ssumK, cntK, fsumA, ssumA, partial);
    k4_reduce<<<1, 256, 0, stream>>>(partial, out);
}

// Round 2
// 36.914 us; speedup vs baseline: 1.5757x; 1.5757x over previous
//
#include <hip/hip_runtime.h>
#include <math.h>

#define B_ 8
#define S_ 2048
#define D_ 128
#define K_ 64
#define SIG_ 0.5f
#define EPS_ 10.0f
#define E_ 2.718281828459045f

// ---------------- K1: per (b,k) class stats via ballot compaction ----------------
// grid = B*K blocks (bx = b*K + k), 128 threads (thread = d)
__global__ void __launch_bounds__(128) k1_stats(
    const float* __restrict__ F, const int* __restrict__ L,
    float* __restrict__ fsumK, float* __restrict__ ssumK, float* __restrict__ cntK,
    int* __restrict__ counter) {
    int bx = blockIdx.x;
    int k = bx & (K_ - 1);
    int b = bx >> 6;
    int tid = threadIdx.x;

    __shared__ int list[S_];
    __shared__ int nrows_s;
    __shared__ float red[128];

    // wave 0: ballot-compact matching row indices (deterministic order)
    if (tid < 64) {
        int base = 0;
        const int* Lb = L + b * S_;
        unsigned long long ltmask = (tid == 63) ? 0x7FFFFFFFFFFFFFFFull
                                                : ((1ull << tid) - 1ull);
        for (int r = 0; r < S_ / 64; ++r) {
            int lbl = Lb[r * 64 + tid];
            unsigned long long m = __ballot(lbl == k);
            if (lbl == k) {
                int pref = __popcll(m & ltmask);
                list[base + pref] = r * 64 + tid;
            }
            base += __popcll(m);
        }
        if (tid == 0) nrows_s = base;
    }
    __syncthreads();
    int n = nrows_s;

    // 128 threads accumulate the ~S/K matching rows (4-way independent chains)
    float fa0 = 0.f, fa1 = 0.f, fa2 = 0.f, fa3 = 0.f;
    float fq0 = 0.f, fq1 = 0.f, fq2 = 0.f, fq3 = 0.f;
    const float* Fb = F + (size_t)b * S_ * D_ + tid;
    int i = 0;
    for (; i + 4 <= n; i += 4) {
        float v0 = Fb[(size_t)list[i + 0] * D_];
        float v1 = Fb[(size_t)list[i + 1] * D_];
        float v2 = Fb[(size_t)list[i + 2] * D_];
        float v3 = Fb[(size_t)list[i + 3] * D_];
        fa0 += v0; fq0 = fmaf(v0, v0, fq0);
        fa1 += v1; fq1 = fmaf(v1, v1, fq1);
        fa2 += v2; fq2 = fmaf(v2, v2, fq2);
        fa3 += v3; fq3 = fmaf(v3, v3, fq3);
    }
    for (; i < n; ++i) {
        float v = Fb[(size_t)list[i] * D_];
        fa0 += v; fq0 = fmaf(v, v, fq0);
    }
    float facc = (fa0 + fa1) + (fa2 + fa3);
    float f2 = (fq0 + fq1) + (fq2 + fq3);

    fsumK[(size_t)bx * D_ + tid] = facc;

    red[tid] = f2;
    __syncthreads();
    if (tid < 64) {
        float v = red[tid] + red[tid + 64];
        #pragma unroll
        for (int m = 1; m < 64; m <<= 1) v += __shfl_xor(v, m);
        if (tid == 0) { ssumK[bx] = v; cntK[bx] = (float)n; }
    }
    if (bx == 0 && tid == 0) *counter = 0;  // stream-ordered init for K3's last-block trick
}

// ---------------- K3: main per-anchor kernel + last-block final reduce ----------------
// grid = 512 blocks x 256 threads; each wave handles one octet (8 anchors)
__global__ void __launch_bounds__(256) k3_main(
    const float* __restrict__ F, const float* __restrict__ C,
    const float* __restrict__ phi, const int* __restrict__ L,
    const float* __restrict__ fsumK, const float* __restrict__ ssumK,
    const float* __restrict__ cntK, float* __restrict__ partial,
    int* __restrict__ counter, float* __restrict__ out) {

    __shared__ float Cs[K_ * 129];   // bank = (k+d)%32 for b32 reads: conflict-free
    __shared__ float Fa[D_];         // per-batch feature sum
    __shared__ float wacc[4];
    __shared__ int isLast;
    int tid = threadIdx.x;
    int b = blockIdx.x >> 6;         // 64 blocks per batch

    for (int i = tid; i < K_ * D_; i += 256) {
        Cs[(i >> 7) * 129 + (i & 127)] = C[i];
    }
    if (tid < 128) {                 // Fa[d] = sum_k fsumK[b,k,d]
        float s = 0.f;
        const float* g = fsumK + (size_t)b * K_ * D_ + tid;
        for (int k = 0; k < K_; ++k) s += g[k * D_];
        Fa[tid] = s;
    }
    __syncthreads();

    int lane = tid & 63;
    int wid = __builtin_amdgcn_readfirstlane(tid) >> 6;

    // per-lane (lane == k) constants
    float c0 = 0.f, c1 = 0.f, c2 = 0.f, c3 = 0.f;
    #pragma unroll
    for (int d = 0; d < D_; d += 4) {
        c0 = fmaf(Cs[lane * 129 + d + 0], Cs[lane * 129 + d + 0], c0);
        c1 = fmaf(Cs[lane * 129 + d + 1], Cs[lane * 129 + d + 1], c1);
        c2 = fmaf(Cs[lane * 129 + d + 2], Cs[lane * 129 + d + 2], c2);
        c3 = fmaf(Cs[lane * 129 + d + 3], Cs[lane * 129 + d + 3], c3);
    }
    float csq = (c0 + c1) + (c2 + c3);
    float phv = phi[lane];
    float ssl = ssumK[b * K_ + lane];
    float cnl = cntK[b * K_ + lane];
    float ssA = ssl;
    #pragma unroll
    for (int m = 1; m < 64; m <<= 1) ssA += __shfl_xor(ssA, m);

    int o = blockIdx.x * 4 + wid;    // octet index
    int a0 = o * 8;                  // anchor base (flat over B*S)
    const float4* F4 = (const float4*)F;

    // ---- phase A: per-anchor sq / dot(fsumK[lbl]) / dot(Fa), 8 lanes per anchor ----
    int j_of = lane >> 3, q = lane & 7;
    int a_mine = a0 + j_of;
    int lbl_p = L[a_mine];
    const float4* fr = F4 + (size_t)a_mine * 32;
    const float4* fk = (const float4*)(fsumK + (size_t)(b * K_ + lbl_p) * D_);
    const float4* fa4 = (const float4*)Fa;

    float sq_p = 0.f, dk_p = 0.f, da_p = 0.f;
    #pragma unroll
    for (int i = 0; i < 4; ++i) {
        int dq = i * 8 + q;
        float4 fv = fr[dq];
        float4 kv = fk[dq];
        float4 av = fa4[dq];
        sq_p = fmaf(fv.x, fv.x, fmaf(fv.y, fv.y, fmaf(fv.z, fv.z, fmaf(fv.w, fv.w, sq_p))));
        dk_p = fmaf(fv.x, kv.x, fmaf(fv.y, kv.y, fmaf(fv.z, kv.z, fmaf(fv.w, kv.w, dk_p))));
        da_p = fmaf(fv.x, av.x, fmaf(fv.y, av.y, fmaf(fv.z, av.z, fmaf(fv.w, av.w, da_p))));
    }
    #pragma unroll
    for (int m = 1; m < 8; m <<= 1) {
        sq_p += __shfl_xor(sq_p, m);
        dk_p += __shfl_xor(dk_p, m);
        da_p += __shfl_xor(da_p, m);
    }

    // ---- phase B: centroid dots, lane = k, wave-uniform feature loads ----
    float facc[8];
    #pragma unroll
    for (int j = 0; j < 8; ++j) facc[j] = 0.f;

    for (int dq = 0; dq < 32; ++dq) {
        float4 fv[8];
        #pragma unroll
        for (int j = 0; j < 8; ++j) fv[j] = F4[(size_t)(a0 + j) * 32 + dq];
        int cbase = lane * 129 + (dq << 2);
        #pragma unroll
        for (int l = 0; l < 4; ++l) {
            float cs = Cs[cbase + l];
            #pragma unroll
            for (int j = 0; j < 8; ++j) {
                float fe = (l == 0) ? fv[j].x : (l == 1) ? fv[j].y : (l == 2) ? fv[j].z : fv[j].w;
                facc[j] = fmaf(fe, cs, facc[j]);
            }
        }
    }

    // ---- phase C: per-anchor scalar epilogue ----
    float acc = 0.f;
    #pragma unroll
    for (int j = 0; j < 8; ++j) {
        float sq_j = __shfl(sq_p, j * 8);
        float dk_j = __shfl(dk_p, j * 8);
        float da_j = __shfl(da_p, j * 8);
        int lbl_j = __shfl(lbl_p, j * 8);
        float cnt_j = __shfl(cnl, lbl_j);
        float ssm_j = __shfl(ssl, lbl_j);

        float cd2 = (sq_j + csq - 2.f * facc[j]) * (1.f / D_);
        cd2 = fmaxf(cd2, 0.f) / phv;

        float s_cd = cd2;
        #pragma unroll
        for (int m = 1; m < 64; m <<= 1) s_cd += __shfl_xor(s_cd, m);
        float pos_cent = __shfl(cd2, lbl_j);

        float ncx = (s_cd - pos_cent) * (1.f / (K_ - 1));
        float S_same = (cnt_j * sq_j + ssm_j - 2.f * dk_j) * (1.f / D_);
        float S_all = ((float)S_ * sq_j + ssA - 2.f * da_j) * (1.f / D_);
        float pos_x = fmaxf(S_same, 0.f) / fmaxf(cnt_j - 1.f, 1.f);
        float neg_cnt = (float)S_ - cnt_j;
        float neg_x = fmaxf(S_all - S_same, 0.f) / fmaxf(neg_cnt, 1.f);

        float neg_sup = neg_x * logf(neg_x + E_);
        float ncl = ncx * logf(ncx + E_);

        float pa = SIG_ * pos_x + (1.f - SIG_) * pos_cent
                 - (SIG_ * neg_sup + (1.f - SIG_) * ncl) + EPS_;
        if (neg_cnt > 0.5f) acc += pa;
    }

    if (lane == 0) wacc[wid] = acc;
    __syncthreads();

    // ---- last-block final reduce ----
    if (tid == 0) {
        float blk = wacc[0] + wacc[1] + wacc[2] + wacc[3];
        __hip_atomic_store(&partial[blockIdx.x], blk, __ATOMIC_RELAXED,
                           __HIP_MEMORY_SCOPE_AGENT);
        int old = __hip_atomic_fetch_add(counter, 1, __ATOMIC_ACQ_REL,
                                         __HIP_MEMORY_SCOPE_AGENT);
        isLast = (old == (int)gridDim.x - 1) ? 1 : 0;
    }
    __syncthreads();
    if (isLast) {
        float v = 0.f;
        for (int i = tid; i < 512; i += 256) {
            v += __hip_atomic_load(&partial[i], __ATOMIC_RELAXED,
                                   __HIP_MEMORY_SCOPE_AGENT);
        }
        #pragma unroll
        for (int m = 1; m < 64; m <<= 1) v += __shfl_xor(v, m);
        if (lane == 0) wacc[wid] = v;
        __syncthreads();
        if (tid == 0) out[0] = (wacc[0] + wacc[1] + wacc[2] + wacc[3]) * (1.0f / (float)S_);
    }
}

extern "C" void kernel_launch(void* const* d_in, const int* in_sizes, int n_in,
                              void* d_out, int out_size, void* d_ws, size_t ws_size,
                              hipStream_t stream) {
    const float* F = (const float*)d_in[0];    // [B,S,D]
    const float* C = (const float*)d_in[1];    // [K,D]
    const float* phi = (const float*)d_in[2];  // [K]
    const int* L = (const int*)d_in[3];        // [B,S]
    float* out = (float*)d_out;

    float* ws = (float*)d_ws;
    float* fsumK = ws;                                // B*K*D = 65536
    float* ssumK = fsumK + (size_t)B_ * K_ * D_;      // 512
    float* cntK  = ssumK + B_ * K_;                   // 512
    float* partial = cntK + B_ * K_;                  // 512
    int* counter = (int*)(partial + 512);             // 1

    k1_stats<<<B_ * K_, 128, 0, stream>>>(F, L, fsumK, ssumK, cntK, counter);
    k3_main<<<512, 256, 0, stream>>>(F, C, phi, L, fsumK, ssumK, cntK, partial, counter, out);
}